// Round 1
// 1434.761 us; speedup vs baseline: 1.0522x; 1.0522x over previous
//
#include <hip/hip_runtime.h>

// ---------- types & helpers ----------
typedef __bf16 v8bf __attribute__((ext_vector_type(8)));
typedef float  v4f  __attribute__((ext_vector_type(4)));

__device__ __forceinline__ float bf2f(unsigned short h) {
    union { unsigned int u; float f; } x; x.u = ((unsigned int)h) << 16; return x.f;
}
__device__ __forceinline__ unsigned short f2bf(float f) {
    union { float f; unsigned int u; } x; x.f = f;
    unsigned int u = x.u;
    u += 0x7fffu + ((u >> 16) & 1u);           // RNE
    return (unsigned short)(u >> 16);
}
// async global->LDS, 16B per lane. LDS dest must be wave-uniform base + lane*16.
__device__ __forceinline__ void gll16(const void* g, void* l) {
    __builtin_amdgcn_global_load_lds((__attribute__((address_space(1))) void*)g,
                                     (__attribute__((address_space(3))) void*)l,
                                     16, 0, 0);
}

// ---------- fp32 -> bf16 elementwise convert (x) ----------
__global__ __launch_bounds__(256) void cvt_f32_bf16(
    const float* __restrict__ in, unsigned short* __restrict__ out)
{
    size_t i = ((size_t)blockIdx.x * 256 + threadIdx.x) * 4;
    float4 v = *(const float4*)&in[i];
    ushort4 o;
    o.x = f2bf(v.x); o.y = f2bf(v.y); o.z = f2bf(v.z); o.w = f2bf(v.w);
    *(ushort4*)&out[i] = o;
}

// ---------- fp32 -> bf16 transposing convert (weights), 64x64 tiles ----------
__global__ __launch_bounds__(256) void transpose_f32_bf16(
    const float* __restrict__ in, unsigned short* __restrict__ out, int ldIn, int M)
{
    __shared__ unsigned short t[64][68];
    const int c0 = blockIdx.x * 64, r0 = blockIdx.y * 64;
    const int lr = threadIdx.x >> 4;
    const int lc = (threadIdx.x & 15) * 4;
#pragma unroll
    for (int i = 0; i < 4; ++i) {
        int row = lr + i * 16;
        float4 v = *(const float4*)&in[(size_t)(r0 + row) * ldIn + c0 + lc];
        ushort4 o;
        o.x = f2bf(v.x); o.y = f2bf(v.y); o.z = f2bf(v.z); o.w = f2bf(v.w);
        *(ushort4*)&t[row][lc] = o;
    }
    __syncthreads();
#pragma unroll
    for (int i = 0; i < 4; ++i) {
        int orow = lr + i * 16;
        ushort4 v;
        v.x = t[lc + 0][orow]; v.y = t[lc + 1][orow];
        v.z = t[lc + 2][orow]; v.w = t[lc + 3][orow];
        *(ushort4*)&out[(size_t)(c0 + orow) * M + r0 + lc] = v;
    }
}

// ---------- GEMM: C[M,N] = A[M,K] * Bt[N,K]^T (bf16 in, fp32 acc) ----------
// Wave map: each wave owns 32 m-rows (2 tiles) x full 128 n (8 tiles) so that
// RoPE pairs (d, d+64) = (acc[i][j], acc[i][j+4]) sit in the SAME lane.
// MODE 0: fp32 store to Cf[M,N].
// MODE 1: RoPE + postScale, bf16 scatter into Ov=[b,h,s,d]      (N=4096)
// MODE 2: bf16 scatter into Ov=V^T [b,h,d,s]                    (N=4096)
template <int MODE>
__global__ __launch_bounds__(256) void gemm_bt(
    const unsigned short* __restrict__ A, const unsigned short* __restrict__ Bt,
    float* __restrict__ Cf, unsigned short* __restrict__ Ov,
    float postScale, int M, int N, int K)
{
    __shared__ unsigned short lA[128 * 32];
    __shared__ unsigned short lB[128 * 32];
    const int tid  = threadIdx.x;
    const int wave = tid >> 6, lane = tid & 63;
    const int quad = lane >> 4, l16 = lane & 15;
    const int m0 = blockIdx.y * 128, n0 = blockIdx.x * 128;

    v4f acc[2][8] = {};

    const unsigned short* Ab = A  + (size_t)(m0 + (tid >> 2)) * K + (tid & 3) * 8;
    const unsigned short* Bb = Bt + (size_t)(n0 + (tid >> 2)) * K + (tid & 3) * 8;

    for (int kt = 0; kt < K; kt += 32) {
        __syncthreads();
        gll16(Ab + kt,                   &lA[tid * 8]);
        gll16(Ab + (size_t)64 * K + kt,  &lA[2048 + tid * 8]);
        gll16(Bb + kt,                   &lB[tid * 8]);
        gll16(Bb + (size_t)64 * K + kt,  &lB[2048 + tid * 8]);
        __syncthreads();

        v8bf af[2], bfr[8];
#pragma unroll
        for (int i = 0; i < 2; ++i)
            af[i] = *(const v8bf*)&lA[(wave * 32 + i * 16 + l16) * 32 + quad * 8];
#pragma unroll
        for (int j = 0; j < 8; ++j)
            bfr[j] = *(const v8bf*)&lB[(j * 16 + l16) * 32 + quad * 8];
#pragma unroll
        for (int i = 0; i < 2; ++i)
#pragma unroll
            for (int j = 0; j < 8; ++j)
                acc[i][j] = __builtin_amdgcn_mfma_f32_16x16x32_bf16(
                    af[i], bfr[j], acc[i][j], 0, 0, 0);
    }

    // C/D layout: col = lane&15, row = quad*4 + reg  [m89-verified]
    if (MODE == 0) {
#pragma unroll
        for (int i = 0; i < 2; ++i) {
            int gm = m0 + wave * 32 + i * 16 + quad * 4;
#pragma unroll
            for (int j = 0; j < 8; ++j) {
                int gn = n0 + j * 16 + l16;
#pragma unroll
                for (int r = 0; r < 4; ++r)
                    Cf[(size_t)(gm + r) * N + gn] = acc[i][j][r];
            }
        }
    } else if (MODE == 1) {
        // RoPE: out[d]    = x[d]*cos - x[d+64]*sin        (d < 64)
        //       out[d+64] = x[d+64]*cos + x[d]*sin
        const int head = n0 >> 7;                  // 128-wide n-tile = 1 head
#pragma unroll
        for (int i = 0; i < 2; ++i) {
            int gmb = m0 + wave * 32 + i * 16 + quad * 4;
            int b = gmb >> 11;
            size_t hb = ((size_t)(b * 32 + head)) << 11;
#pragma unroll
            for (int j = 0; j < 4; ++j) {
                int d1 = j * 16 + l16;             // 0..63
                float inv = powf(10000.0f, -(float)d1 * 0.015625f);
#pragma unroll
                for (int r = 0; r < 4; ++r) {
                    int s = (gmb + r) & 2047;
                    float ang = (float)s * inv, sn, cs;
                    sincosf(ang, &sn, &cs);
                    float x1 = acc[i][j][r], x2 = acc[i][j + 4][r];
                    size_t a = (hb + s) << 7;
                    Ov[a + d1]      = f2bf((x1 * cs - x2 * sn) * postScale);
                    Ov[a + d1 + 64] = f2bf((x2 * cs + x1 * sn) * postScale);
                }
            }
        }
    } else {
        // V^T: Ov[bh][d][s], s contiguous -> pack 4 rows as ushort4
        const int head = n0 >> 7;
#pragma unroll
        for (int i = 0; i < 2; ++i) {
            int gmb = m0 + wave * 32 + i * 16 + quad * 4;
            int b = gmb >> 11, s0 = gmb & 2047;
            size_t bb = ((size_t)(b * 32 + head)) << 18;   // *128*2048
#pragma unroll
            for (int j = 0; j < 8; ++j) {
                int d = j * 16 + l16;
                ushort4 o;
                o.x = f2bf(acc[i][j][0]); o.y = f2bf(acc[i][j][1]);
                o.z = f2bf(acc[i][j][2]); o.w = f2bf(acc[i][j][3]);
                *(ushort4*)&Ov[bb + ((size_t)d << 11) + s0] = o;
            }
        }
    }
}

// ---------- causal flash attention, swapped-operand / in-register P ----------
// Q,K: [b*32+h][s][128] (Q pre-scaled); Vt: [b*32+h][128][s];
// ctx out: [(b*2048+s)][h*128+d] bf16
//
// All q-indexed state is lane-local (q = lane&15):
//   S^T  = mfma(A=K,  B=Q):  D[row=kv_loc=quad*4+r][col=q=l16]
//   O^T += mfma(A=V^T,B=P^T):D[row=d_loc =quad*4+r][col=q=l16]
// P exchange (D-layout -> B-layout) is a pure cross-quad permutation at
// fixed l16: 8 shfl + 4 selects per 32-kv tile; no LDS, no fence.
// KVBLK=32 double-buffered: LDS = 32 KiB exactly -> 5 blocks/CU.
__global__ __launch_bounds__(256, 5) void attn_kernel(
    const unsigned short* __restrict__ Q, const unsigned short* __restrict__ Kg,
    const unsigned short* __restrict__ Vt, unsigned short* __restrict__ ctx)
{
    __shared__ unsigned short lK[2][32 * 128];   // [kv][d], chunk-swizzled ^ (row&15)
    __shared__ unsigned short lV[2][128 * 32];   // [d][kv], chunk-swizzled ^ ((row>>1)&3)

    const int qt  = gridDim.x - 1 - blockIdx.x;  // long blocks dispatched first
    const int bh  = blockIdx.y;
    const int tid = threadIdx.x;
    const int wave = tid >> 6, lane = tid & 63;
    const int quad = lane >> 4, l16 = lane & 15;
    const int q0 = qt * 64;
    const size_t base = (size_t)bh << 18;        // *2048*128

    // stage one 32-kv tile (K 32x128 + Vt 128x32) into buffer `buf`
    auto stage = [&](int kv0, int buf) {
#pragma unroll
        for (int it = 0; it < 2; ++it) {
            int cid = it * 256 + tid;
            int row = cid >> 4, chk = cid & 15;
            gll16(Kg + base + ((size_t)(kv0 + row) << 7) + ((chk ^ (row & 15)) << 3),
                  &lK[buf][cid << 3]);
        }
#pragma unroll
        for (int it = 0; it < 2; ++it) {
            int cid = it * 256 + tid;
            int row = cid >> 2, chk = cid & 3;
            gll16(Vt + base + ((size_t)row << 11) + kv0 + ((chk ^ ((row >> 1) & 3)) << 3),
                  &lV[buf][cid << 3]);
        }
    };

    // Q fragments (B-operand: n = lane&15 = q, k = quad*8+j), rows q0+wave*16+l16
    v8bf qf[4];
    {
        const unsigned short* qrow =
            Q + base + ((size_t)(q0 + wave * 16 + l16) << 7) + quad * 8;
#pragma unroll
        for (int kc = 0; kc < 4; ++kc)
            qf[kc] = *(const v8bf*)(qrow + kc * 32);
    }

    const int qg = q0 + wave * 16 + l16;         // this lane's q row
    float mrow = -1e30f, lrow = 0.f;
    v4f Oa[8] = {};
    const float c2 = 1.4426950408889634f;        // log2(e); scale folded into Q

    const int nkt = 2 * qt + 2;
    stage(0, 0);
    for (int kt = 0; kt < nkt; ++kt) {
        const int cur = kt & 1;
        // barrier: (a) compiler-emitted vmcnt(0) completes tile kt's loads,
        // (b) all waves done reading buf cur^1 -> safe to prefetch into it
        __syncthreads();
        if (kt + 1 < nkt) stage((kt + 1) * 32, cur ^ 1);  // flies during compute

        const unsigned short* K_ = &lK[cur][0];
        const unsigned short* V_ = &lV[cur][0];
        const int kv0 = kt * 32;

        // S^T = K Q^T  (kv = kv0 + nt*16 + quad*4 + r, q = l16)
        v4f sc[2] = {};
#pragma unroll
        for (int kc = 0; kc < 4; ++kc) {
#pragma unroll
            for (int nt = 0; nt < 2; ++nt) {
                v8bf kf = *(const v8bf*)&K_[((nt * 16 + l16) << 7) +
                                            ((((kc << 2) + quad) ^ l16) << 3)];
                sc[nt] = __builtin_amdgcn_mfma_f32_16x16x32_bf16(kf, qf[kc], sc[nt], 0, 0, 0);
            }
        }

        if (kt >= nkt - 2) {  // diagonal region: causal mask
#pragma unroll
            for (int nt = 0; nt < 2; ++nt) {
                int kvb = kv0 + nt * 16 + quad * 4;
#pragma unroll
                for (int r = 0; r < 4; ++r)
                    if (kvb + r > qg) sc[nt][r] = -1e30f;
            }
        }

        // online softmax: row q=l16 entirely lane-local (8 vals) + cross-quad
        float tmax = fmaxf(fmaxf(fmaxf(sc[0][0], sc[0][1]), fmaxf(sc[0][2], sc[0][3])),
                           fmaxf(fmaxf(sc[1][0], sc[1][1]), fmaxf(sc[1][2], sc[1][3])));
        tmax = fmaxf(tmax, __shfl_xor(tmax, 16));
        tmax = fmaxf(tmax, __shfl_xor(tmax, 32));

        float mnew = fmaxf(mrow, tmax);
        float alpha = exp2f((mrow - mnew) * c2);
        mrow = mnew;
        const float mc = mnew * c2;
        float rsum = 0.f;
#pragma unroll
        for (int nt = 0; nt < 2; ++nt)
#pragma unroll
            for (int r = 0; r < 4; ++r) {
                float p = exp2f(fmaf(sc[nt][r], c2, -mc));
                sc[nt][r] = p;
                rsum += p;
            }
        rsum += __shfl_xor(rsum, 16);
        rsum += __shfl_xor(rsum, 32);
        lrow = lrow * alpha + rsum;
#pragma unroll
        for (int d8 = 0; d8 < 8; ++d8)
#pragma unroll
            for (int r = 0; r < 4; ++r)
                Oa[d8][r] *= alpha;

        // P: D-layout -> B-layout in registers.
        // dest (quad,l16) needs P[q=l16][kv=quad*8+2*j2+{0,1}] in dword j2:
        //   src lane = ((quad&1)*2 + (j2>>1))*16 + l16
        //   src reg  = pk[quad>>1][j2&1]
        unsigned int pk0[2], pk1[2];
#pragma unroll
        for (int h = 0; h < 2; ++h) {
            pk0[h] = (unsigned int)f2bf(sc[0][2 * h]) |
                     ((unsigned int)f2bf(sc[0][2 * h + 1]) << 16);
            pk1[h] = (unsigned int)f2bf(sc[1][2 * h]) |
                     ((unsigned int)f2bf(sc[1][2 * h + 1]) << 16);
        }
        union { unsigned int u[4]; v8bf v; } pu;
        const int sbase = ((quad & 1) << 5) + l16;
#pragma unroll
        for (int j2 = 0; j2 < 4; ++j2) {
            int src = sbase + ((j2 >> 1) << 4);
            int a = __shfl((int)pk0[j2 & 1], src);
            int b = __shfl((int)pk1[j2 & 1], src);
            pu.u[j2] = (quad < 2) ? (unsigned int)a : (unsigned int)b;
        }
        v8bf pf = pu.v;

        // O^T += V^T P^T  (d = dt*16 + quad*4 + r, q = l16)
#pragma unroll
        for (int dt = 0; dt < 8; ++dt) {
            v8bf vf = *(const v8bf*)&V_[((dt * 16 + l16) << 5) +
                                        ((quad ^ ((l16 >> 1) & 3)) << 3)];
            Oa[dt] = __builtin_amdgcn_mfma_f32_16x16x32_bf16(vf, pf, Oa[dt], 0, 0, 0);
        }
    }

    // epilogue: ctx[(b*2048+q)*4096 + h*128 + d]; q lane-local, d = dt*16+quad*4+r
    const int b = bh >> 5, h = bh & 31;
    const float invl = 1.0f / lrow;
    size_t rowb = ((size_t)(b * 2048 + qg) << 12) + ((size_t)h << 7);
#pragma unroll
    for (int dt = 0; dt < 8; ++dt) {
        ushort4 o;
        o.x = f2bf(Oa[dt][0] * invl);
        o.y = f2bf(Oa[dt][1] * invl);
        o.z = f2bf(Oa[dt][2] * invl);
        o.w = f2bf(Oa[dt][3] * invl);
        *(ushort4*)&ctx[rowb + dt * 16 + quad * 4] = o;
    }
}

// ---------- launch ----------
extern "C" void kernel_launch(void* const* d_in, const int* in_sizes, int n_in,
                              void* d_out, int out_size, void* d_ws, size_t ws_size,
                              hipStream_t stream)
{
    const float* x    = (const float*)d_in[0];   // (2,2048,4096) fp32
    const float* Wqkv = (const float*)d_in[1];   // (4096,12288)  fp32
    const float* Wo   = (const float*)d_in[2];   // (4096,4096)   fp32
    float* out = (float*)d_out;                  // (2,2048,4096) fp32

    char* ws = (char*)d_ws;
    const size_t B32 = (size_t)32 * 1024 * 1024;
    unsigned short* B0 = (unsigned short*)(ws);              // xb, later ctx
    unsigned short* B1 = (unsigned short*)(ws + 1 * B32);    // Q (pre-scaled, roped)
    unsigned short* B2 = (unsigned short*)(ws + 2 * B32);    // K (roped)
    unsigned short* B3 = (unsigned short*)(ws + 3 * B32);    // V^T
    unsigned short* B4 = (unsigned short*)(ws + 4 * B32);    // weight chunk / Wo^T
    // total ws use: 160 MiB

    const float qscale = 0.08838834764831845f;   // 1/sqrt(128)

    // 1. x -> bf16
    cvt_f32_bf16<<<16384, 256, 0, stream>>>(x, B0);
    // 2. chunk 0: Q = rope(x*Wq) * qscale  -> B1 [b,h,s,d]
    transpose_f32_bf16<<<dim3(64, 64), 256, 0, stream>>>(Wqkv, B4, 12288, 4096);
    gemm_bt<1><<<dim3(32, 32), 256, 0, stream>>>(B0, B4, nullptr, B1, qscale,
                                                 4096, 4096, 4096);
    // 3. chunk 1: K = rope(x*Wk) -> B2 [b,h,s,d]
    transpose_f32_bf16<<<dim3(64, 64), 256, 0, stream>>>(Wqkv + 4096, B4, 12288, 4096);
    gemm_bt<1><<<dim3(32, 32), 256, 0, stream>>>(B0, B4, nullptr, B2, 1.0f,
                                                 4096, 4096, 4096);
    // 4. chunk 2: V^T = (x*Wv)^T -> B3 [b,h,d,s]
    transpose_f32_bf16<<<dim3(64, 64), 256, 0, stream>>>(Wqkv + 8192, B4, 12288, 4096);
    gemm_bt<2><<<dim3(32, 32), 256, 0, stream>>>(B0, B4, nullptr, B3, 1.0f,
                                                 4096, 4096, 4096);
    // 5. Wo^T -> B4
    transpose_f32_bf16<<<dim3(64, 64), 256, 0, stream>>>(Wo, B4, 4096, 4096);
    // 6. flash attention -> ctx (B0; xb dead after chunk GEMMs)
    attn_kernel<<<dim3(32, 64), 256, 0, stream>>>(B1, B2, B3, B0);
    // 7. output projection: ctx * Wo -> fp32 out
    gemm_bt<0><<<dim3(32, 32), 256, 0, stream>>>(B0, B4, out, nullptr, 1.0f,
                                                 4096, 4096, 4096);
}

// Round 2
// 1142.138 us; speedup vs baseline: 1.3217x; 1.2562x over previous
//
#include <hip/hip_runtime.h>

// ---------- types & helpers ----------
typedef __bf16 v8bf __attribute__((ext_vector_type(8)));
typedef float  v4f  __attribute__((ext_vector_type(4)));

__device__ __forceinline__ float bf2f(unsigned short h) {
    union { unsigned int u; float f; } x; x.u = ((unsigned int)h) << 16; return x.f;
}
__device__ __forceinline__ unsigned short f2bf(float f) {
    union { float f; unsigned int u; } x; x.f = f;
    unsigned int u = x.u;
    u += 0x7fffu + ((u >> 16) & 1u);           // RNE
    return (unsigned short)(u >> 16);
}
// async global->LDS, 16B per lane. LDS dest must be wave-uniform base + lane*16.
__device__ __forceinline__ void gll16(const void* g, void* l) {
    __builtin_amdgcn_global_load_lds((__attribute__((address_space(1))) void*)g,
                                     (__attribute__((address_space(3))) void*)l,
                                     16, 0, 0);
}

// ---------- fp32 -> bf16 elementwise convert (x) ----------
__global__ __launch_bounds__(256) void cvt_f32_bf16(
    const float* __restrict__ in, unsigned short* __restrict__ out)
{
    size_t i = ((size_t)blockIdx.x * 256 + threadIdx.x) * 4;
    float4 v = *(const float4*)&in[i];
    ushort4 o;
    o.x = f2bf(v.x); o.y = f2bf(v.y); o.z = f2bf(v.z); o.w = f2bf(v.w);
    *(ushort4*)&out[i] = o;
}

// ---------- fp32 -> bf16 transposing convert (weights), 64x64 tiles ----------
__global__ __launch_bounds__(256) void transpose_f32_bf16(
    const float* __restrict__ in, unsigned short* __restrict__ out, int ldIn, int M)
{
    __shared__ unsigned short t[64][68];
    const int c0 = blockIdx.x * 64, r0 = blockIdx.y * 64;
    const int lr = threadIdx.x >> 4;
    const int lc = (threadIdx.x & 15) * 4;
#pragma unroll
    for (int i = 0; i < 4; ++i) {
        int row = lr + i * 16;
        float4 v = *(const float4*)&in[(size_t)(r0 + row) * ldIn + c0 + lc];
        ushort4 o;
        o.x = f2bf(v.x); o.y = f2bf(v.y); o.z = f2bf(v.z); o.w = f2bf(v.w);
        *(ushort4*)&t[row][lc] = o;
    }
    __syncthreads();
#pragma unroll
    for (int i = 0; i < 4; ++i) {
        int orow = lr + i * 16;
        ushort4 v;
        v.x = t[lc + 0][orow]; v.y = t[lc + 1][orow];
        v.z = t[lc + 2][orow]; v.w = t[lc + 3][orow];
        *(ushort4*)&out[(size_t)(c0 + orow) * M + r0 + lc] = v;
    }
}

// ---------- 256x256 pipelined GEMM: C[4096,4096] = A * Bt^T (bf16, fp32 acc) ----
// 512 threads / 8 waves (2 m-groups x 4 n-groups). BK=32, ring of 4 LDS buffers
// (128 KiB), prefetch distance 3 K-steps, counted vmcnt(8) once per K-step.
// Per wave: 128 rows x 64 cols, cols interleaved as ni*64 + wc*16 so that RoPE
// pairs (d, d+64) land in the same lane (acc[mi][0]<->[1], [2]<->[3]).
// LDS XOR chunk swizzle: LDS[row][c] holds global[row][c ^ ((row>>1)&3)] (16B
// chunks); reads use chunk = quad ^ ((l16>>1)&3)  -> conflict-free ds_read_b128.
// MODE 0: fp32 store to Cf.  MODE 1: RoPE+postScale scatter to Ov=[b,h,s,d].
// MODE 2: scatter to Ov = V^T [b,h,d,s].
template <int MODE>
__global__ __launch_bounds__(512, 2) void gemm256(
    const unsigned short* __restrict__ A, const unsigned short* __restrict__ Bt,
    float* __restrict__ Cf, unsigned short* __restrict__ Ov, float postScale)
{
    constexpr int NT = 128;                       // K/32 = 4096/32
    __shared__ unsigned short lA[4][8192];        // 4 bufs x 256 rows x 32 el
    __shared__ unsigned short lB[4][8192];
    const int tid = threadIdx.x;
    const int wave = tid >> 6, lane = tid & 63;
    const int quad = lane >> 4, l16 = lane & 15;
    const int wr = wave >> 2, wc = wave & 3;

    // bijective XCD swizzle (nwg=256, 8 XCDs): same-XCD blocks share A panels
    const int bid = blockIdx.x;
    const int swz = (bid & 7) * 32 + (bid >> 3);
    const int m0 = (swz >> 4) * 256, n0 = (swz & 15) * 256;

    v4f acc[8][4] = {};

    // staging source pointers (pre-swizzled global so LDS dest stays linear)
    const int sr0 = tid >> 2, sc0 = tid & 3;
    const int sr1 = 128 + sr0;
    const unsigned short* pA0 = A  + (size_t)(m0 + sr0) * 4096 + ((sc0 ^ ((sr0 >> 1) & 3)) << 3);
    const unsigned short* pA1 = A  + (size_t)(m0 + sr1) * 4096 + ((sc0 ^ ((sr1 >> 1) & 3)) << 3);
    const unsigned short* pB0 = Bt + (size_t)(n0 + sr0) * 4096 + ((sc0 ^ ((sr0 >> 1) & 3)) << 3);
    const unsigned short* pB1 = Bt + (size_t)(n0 + sr1) * 4096 + ((sc0 ^ ((sr1 >> 1) & 3)) << 3);

    auto stA = [&](int t3) {
        int cb = t3 & 3; size_t ko = (size_t)t3 << 5;
        gll16(pA0 + ko, &lA[cb][tid * 8]);
        gll16(pA1 + ko, &lA[cb][4096 + tid * 8]);
    };
    auto stB = [&](int t3) {
        int cb = t3 & 3; size_t ko = (size_t)t3 << 5;
        gll16(pB0 + ko, &lB[cb][tid * 8]);
        gll16(pB1 + ko, &lB[cb][4096 + tid * 8]);
    };

    // prologue: 3 K-steps in flight
    stA(0); stB(0); stA(1); stB(1); stA(2); stB(2);
    asm volatile("s_waitcnt vmcnt(8)" ::: "memory");   // stage(0) landed
    __builtin_amdgcn_s_barrier();

    const int swzk = (l16 >> 1) & 3;
    const int aoff = (wr * 128 + l16) * 32 + ((quad ^ swzk) << 3);
    const int boff = (wc * 16  + l16) * 32 + ((quad ^ swzk) << 3);

#pragma unroll 4
    for (int t = 0; t < NT; ++t) {
        const int cur = t & 3;
        const unsigned short* lAc = &lA[cur][0];
        const unsigned short* lBc = &lB[cur][0];
        v8bf a[8], b0, b1;
        // ---- phase 0: A frags(8) + B ni0/ni1; stage A(t+3); 16 MFMA ----
#pragma unroll
        for (int mi = 0; mi < 8; ++mi)
            a[mi] = *(const v8bf*)&lAc[aoff + mi * 512];
        b0 = *(const v8bf*)&lBc[boff];                 // cols [wc*16, ..)
        b1 = *(const v8bf*)&lBc[boff + 2048];          // cols [64+wc*16, ..)
        if (t + 3 < NT) stA(t + 3);                    // buf (t-1)&3: reads done
        __builtin_amdgcn_s_barrier();
        __builtin_amdgcn_s_setprio(1);
#pragma unroll
        for (int mi = 0; mi < 8; ++mi) {
            acc[mi][0] = __builtin_amdgcn_mfma_f32_16x16x32_bf16(a[mi], b0, acc[mi][0], 0, 0, 0);
            acc[mi][1] = __builtin_amdgcn_mfma_f32_16x16x32_bf16(a[mi], b1, acc[mi][1], 0, 0, 0);
        }
        __builtin_amdgcn_s_setprio(0);
        __builtin_amdgcn_s_barrier();
        // ---- phase 1: B ni2/ni3; stage B(t+3); vmcnt gate; 16 MFMA ----
        b0 = *(const v8bf*)&lBc[boff + 4096];
        b1 = *(const v8bf*)&lBc[boff + 6144];
        if (t + 3 < NT) stB(t + 3);
        // gate: stage(t+1) fully landed (8 newest loads = stages t+2, t+3)
        if (t < NT - 3)       asm volatile("s_waitcnt vmcnt(8)" ::: "memory");
        else if (t == NT - 3) asm volatile("s_waitcnt vmcnt(4)" ::: "memory");
        else if (t == NT - 2) asm volatile("s_waitcnt vmcnt(0)" ::: "memory");
        __builtin_amdgcn_s_barrier();
        __builtin_amdgcn_s_setprio(1);
#pragma unroll
        for (int mi = 0; mi < 8; ++mi) {
            acc[mi][2] = __builtin_amdgcn_mfma_f32_16x16x32_bf16(a[mi], b0, acc[mi][2], 0, 0, 0);
            acc[mi][3] = __builtin_amdgcn_mfma_f32_16x16x32_bf16(a[mi], b1, acc[mi][3], 0, 0, 0);
        }
        __builtin_amdgcn_s_setprio(0);
        __builtin_amdgcn_s_barrier();
    }

    // ---- epilogue; D layout: row(m) = quad*4+r, col(n) = l16 ----
    if (MODE == 0) {
#pragma unroll
        for (int mi = 0; mi < 8; ++mi) {
            int gm = m0 + wr * 128 + mi * 16 + quad * 4;
#pragma unroll
            for (int ni = 0; ni < 4; ++ni) {
                int gn = n0 + ni * 64 + wc * 16 + l16;
#pragma unroll
                for (int r = 0; r < 4; ++r)
                    Cf[(size_t)(gm + r) * 4096 + gn] = acc[mi][ni][r];
            }
        }
    } else if (MODE == 1) {
        // RoPE: pairs (d1, d1+64) = (acc[mi][2h], acc[mi][2h+1]) same lane
        const int d1 = wc * 16 + l16;                  // 0..63
        const float inv = powf(10000.0f, -(float)d1 * 0.015625f);
        const int head0 = n0 >> 7;                     // 2 heads per 256-n block
#pragma unroll
        for (int mi = 0; mi < 8; ++mi) {
            int gmb = m0 + wr * 128 + mi * 16 + quad * 4;
            int b = gmb >> 11, sb = gmb & 2047;
            float sn[4], cs[4];
#pragma unroll
            for (int r = 0; r < 4; ++r)
                sincosf((float)(sb + r) * inv, &sn[r], &cs[r]);
#pragma unroll
            for (int hd = 0; hd < 2; ++hd) {
                size_t hb = ((size_t)(b * 32 + head0 + hd)) << 11;
#pragma unroll
                for (int r = 0; r < 4; ++r) {
                    float x1 = acc[mi][2 * hd][r], x2 = acc[mi][2 * hd + 1][r];
                    size_t adr = (hb + sb + r) << 7;
                    Ov[adr + d1]      = f2bf((x1 * cs[r] - x2 * sn[r]) * postScale);
                    Ov[adr + d1 + 64] = f2bf((x2 * cs[r] + x1 * sn[r]) * postScale);
                }
            }
        }
    } else {
        // V^T: Ov[bh][d][s], s contiguous -> pack 4 rows as ushort4
        const int head0 = n0 >> 7;
#pragma unroll
        for (int mi = 0; mi < 8; ++mi) {
            int gmb = m0 + wr * 128 + mi * 16 + quad * 4;
            int b = gmb >> 11, s0 = gmb & 2047;
#pragma unroll
            for (int ni = 0; ni < 4; ++ni) {
                int head = head0 + (ni >> 1);
                int d = ((ni & 1) << 6) + wc * 16 + l16;
                ushort4 o;
                o.x = f2bf(acc[mi][ni][0]); o.y = f2bf(acc[mi][ni][1]);
                o.z = f2bf(acc[mi][ni][2]); o.w = f2bf(acc[mi][ni][3]);
                *(ushort4*)&Ov[(((size_t)(b * 32 + head)) << 18) +
                               ((size_t)d << 11) + s0] = o;
            }
        }
    }
}

// ---------- causal flash attention, swapped-operand / in-register P ----------
// (unchanged from previous round: 290 us, KVBLK=32 dbuf, 5 blocks/CU)
__global__ __launch_bounds__(256, 5) void attn_kernel(
    const unsigned short* __restrict__ Q, const unsigned short* __restrict__ Kg,
    const unsigned short* __restrict__ Vt, unsigned short* __restrict__ ctx)
{
    __shared__ unsigned short lK[2][32 * 128];
    __shared__ unsigned short lV[2][128 * 32];

    const int qt  = gridDim.x - 1 - blockIdx.x;
    const int bh  = blockIdx.y;
    const int tid = threadIdx.x;
    const int wave = tid >> 6, lane = tid & 63;
    const int quad = lane >> 4, l16 = lane & 15;
    const int q0 = qt * 64;
    const size_t base = (size_t)bh << 18;

    auto stage = [&](int kv0, int buf) {
#pragma unroll
        for (int it = 0; it < 2; ++it) {
            int cid = it * 256 + tid;
            int row = cid >> 4, chk = cid & 15;
            gll16(Kg + base + ((size_t)(kv0 + row) << 7) + ((chk ^ (row & 15)) << 3),
                  &lK[buf][cid << 3]);
        }
#pragma unroll
        for (int it = 0; it < 2; ++it) {
            int cid = it * 256 + tid;
            int row = cid >> 2, chk = cid & 3;
            gll16(Vt + base + ((size_t)row << 11) + kv0 + ((chk ^ ((row >> 1) & 3)) << 3),
                  &lV[buf][cid << 3]);
        }
    };

    v8bf qf[4];
    {
        const unsigned short* qrow =
            Q + base + ((size_t)(q0 + wave * 16 + l16) << 7) + quad * 8;
#pragma unroll
        for (int kc = 0; kc < 4; ++kc)
            qf[kc] = *(const v8bf*)(qrow + kc * 32);
    }

    const int qg = q0 + wave * 16 + l16;
    float mrow = -1e30f, lrow = 0.f;
    v4f Oa[8] = {};
    const float c2 = 1.4426950408889634f;

    const int nkt = 2 * qt + 2;
    stage(0, 0);
    for (int kt = 0; kt < nkt; ++kt) {
        const int cur = kt & 1;
        __syncthreads();
        if (kt + 1 < nkt) stage((kt + 1) * 32, cur ^ 1);

        const unsigned short* K_ = &lK[cur][0];
        const unsigned short* V_ = &lV[cur][0];
        const int kv0 = kt * 32;

        v4f sc[2] = {};
#pragma unroll
        for (int kc = 0; kc < 4; ++kc) {
#pragma unroll
            for (int nt = 0; nt < 2; ++nt) {
                v8bf kf = *(const v8bf*)&K_[((nt * 16 + l16) << 7) +
                                            ((((kc << 2) + quad) ^ l16) << 3)];
                sc[nt] = __builtin_amdgcn_mfma_f32_16x16x32_bf16(kf, qf[kc], sc[nt], 0, 0, 0);
            }
        }

        if (kt >= nkt - 2) {
#pragma unroll
            for (int nt = 0; nt < 2; ++nt) {
                int kvb = kv0 + nt * 16 + quad * 4;
#pragma unroll
                for (int r = 0; r < 4; ++r)
                    if (kvb + r > qg) sc[nt][r] = -1e30f;
            }
        }

        float tmax = fmaxf(fmaxf(fmaxf(sc[0][0], sc[0][1]), fmaxf(sc[0][2], sc[0][3])),
                           fmaxf(fmaxf(sc[1][0], sc[1][1]), fmaxf(sc[1][2], sc[1][3])));
        tmax = fmaxf(tmax, __shfl_xor(tmax, 16));
        tmax = fmaxf(tmax, __shfl_xor(tmax, 32));

        float mnew = fmaxf(mrow, tmax);
        float alpha = exp2f((mrow - mnew) * c2);
        mrow = mnew;
        const float mc = mnew * c2;
        float rsum = 0.f;
#pragma unroll
        for (int nt = 0; nt < 2; ++nt)
#pragma unroll
            for (int r = 0; r < 4; ++r) {
                float p = exp2f(fmaf(sc[nt][r], c2, -mc));
                sc[nt][r] = p;
                rsum += p;
            }
        rsum += __shfl_xor(rsum, 16);
        rsum += __shfl_xor(rsum, 32);
        lrow = lrow * alpha + rsum;
#pragma unroll
        for (int d8 = 0; d8 < 8; ++d8)
#pragma unroll
            for (int r = 0; r < 4; ++r)
                Oa[d8][r] *= alpha;

        unsigned int pk0[2], pk1[2];
#pragma unroll
        for (int h = 0; h < 2; ++h) {
            pk0[h] = (unsigned int)f2bf(sc[0][2 * h]) |
                     ((unsigned int)f2bf(sc[0][2 * h + 1]) << 16);
            pk1[h] = (unsigned int)f2bf(sc[1][2 * h]) |
                     ((unsigned int)f2bf(sc[1][2 * h + 1]) << 16);
        }
        union { unsigned int u[4]; v8bf v; } pu;
        const int sbase = ((quad & 1) << 5) + l16;
#pragma unroll
        for (int j2 = 0; j2 < 4; ++j2) {
            int src = sbase + ((j2 >> 1) << 4);
            int a = __shfl((int)pk0[j2 & 1], src);
            int b = __shfl((int)pk1[j2 & 1], src);
            pu.u[j2] = (quad < 2) ? (unsigned int)a : (unsigned int)b;
        }
        v8bf pf = pu.v;

#pragma unroll
        for (int dt = 0; dt < 8; ++dt) {
            v8bf vf = *(const v8bf*)&V_[((dt * 16 + l16) << 5) +
                                        ((quad ^ ((l16 >> 1) & 3)) << 3)];
            Oa[dt] = __builtin_amdgcn_mfma_f32_16x16x32_bf16(vf, pf, Oa[dt], 0, 0, 0);
        }
    }

    const int b = bh >> 5, h = bh & 31;
    const float invl = 1.0f / lrow;
    size_t rowb = ((size_t)(b * 2048 + qg) << 12) + ((size_t)h << 7);
#pragma unroll
    for (int dt = 0; dt < 8; ++dt) {
        ushort4 o;
        o.x = f2bf(Oa[dt][0] * invl);
        o.y = f2bf(Oa[dt][1] * invl);
        o.z = f2bf(Oa[dt][2] * invl);
        o.w = f2bf(Oa[dt][3] * invl);
        *(ushort4*)&ctx[rowb + dt * 16 + quad * 4] = o;
    }
}

// ---------- launch ----------
extern "C" void kernel_launch(void* const* d_in, const int* in_sizes, int n_in,
                              void* d_out, int out_size, void* d_ws, size_t ws_size,
                              hipStream_t stream)
{
    const float* x    = (const float*)d_in[0];   // (2,2048,4096) fp32
    const float* Wqkv = (const float*)d_in[1];   // (4096,12288)  fp32
    const float* Wo   = (const float*)d_in[2];   // (4096,4096)   fp32
    float* out = (float*)d_out;                  // (2,2048,4096) fp32

    char* ws = (char*)d_ws;
    const size_t B32 = (size_t)32 * 1024 * 1024;
    unsigned short* B0 = (unsigned short*)(ws);              // xb, later ctx
    unsigned short* B1 = (unsigned short*)(ws + 1 * B32);    // Q (pre-scaled, roped)
    unsigned short* B2 = (unsigned short*)(ws + 2 * B32);    // K (roped)
    unsigned short* B3 = (unsigned short*)(ws + 3 * B32);    // V^T
    unsigned short* B4 = (unsigned short*)(ws + 4 * B32);    // weight chunk / Wo^T

    const float qscale = 0.08838834764831845f;   // 1/sqrt(128)

    // 1. x -> bf16
    cvt_f32_bf16<<<16384, 256, 0, stream>>>(x, B0);
    // 2. chunk 0: Q = rope(x*Wq) * qscale  -> B1 [b,h,s,d]
    transpose_f32_bf16<<<dim3(64, 64), 256, 0, stream>>>(Wqkv, B4, 12288, 4096);
    gemm256<1><<<256, 512, 0, stream>>>(B0, B4, nullptr, B1, qscale);
    // 3. chunk 1: K = rope(x*Wk) -> B2 [b,h,s,d]
    transpose_f32_bf16<<<dim3(64, 64), 256, 0, stream>>>(Wqkv + 4096, B4, 12288, 4096);
    gemm256<1><<<256, 512, 0, stream>>>(B0, B4, nullptr, B2, 1.0f);
    // 4. chunk 2: V^T = (x*Wv)^T -> B3 [b,h,d,s]
    transpose_f32_bf16<<<dim3(64, 64), 256, 0, stream>>>(Wqkv + 8192, B4, 12288, 4096);
    gemm256<2><<<256, 512, 0, stream>>>(B0, B4, nullptr, B3, 1.0f);
    // 5. Wo^T -> B4
    transpose_f32_bf16<<<dim3(64, 64), 256, 0, stream>>>(Wo, B4, 4096, 4096);
    // 6. flash attention -> ctx (B0; xb dead after chunk GEMMs)
    attn_kernel<<<dim3(32, 64), 256, 0, stream>>>(B1, B2, B3, B0);
    // 7. output projection: ctx * Wo -> fp32 out
    gemm256<0><<<256, 512, 0, stream>>>(B0, B4, out, nullptr, 1.0f);
}

// Round 3
// 1079.397 us; speedup vs baseline: 1.3986x; 1.0581x over previous
//
#include <hip/hip_runtime.h>

// ---------- types & helpers ----------
typedef __bf16 v8bf __attribute__((ext_vector_type(8)));
typedef float  v4f  __attribute__((ext_vector_type(4)));

__device__ __forceinline__ float bf2f(unsigned short h) {
    union { unsigned int u; float f; } x; x.u = ((unsigned int)h) << 16; return x.f;
}
__device__ __forceinline__ unsigned short f2bf(float f) {
    union { float f; unsigned int u; } x; x.f = f;
    unsigned int u = x.u;
    u += 0x7fffu + ((u >> 16) & 1u);           // RNE
    return (unsigned short)(u >> 16);
}
// async global->LDS, 16B per lane. LDS dest must be wave-uniform base + lane*16.
__device__ __forceinline__ void gll16(const void* g, void* l) {
    __builtin_amdgcn_global_load_lds((__attribute__((address_space(1))) void*)g,
                                     (__attribute__((address_space(3))) void*)l,
                                     16, 0, 0);
}

// ---------- fp32 -> bf16 elementwise convert (x) ----------
__global__ __launch_bounds__(256) void cvt_f32_bf16(
    const float* __restrict__ in, unsigned short* __restrict__ out)
{
    size_t i = ((size_t)blockIdx.x * 256 + threadIdx.x) * 4;
    float4 v = *(const float4*)&in[i];
    ushort4 o;
    o.x = f2bf(v.x); o.y = f2bf(v.y); o.z = f2bf(v.z); o.w = f2bf(v.w);
    *(ushort4*)&out[i] = o;
}

// ---------- fp32 -> bf16 transposing convert (weights), 64x64 tiles ----------
__global__ __launch_bounds__(256) void transpose_f32_bf16(
    const float* __restrict__ in, unsigned short* __restrict__ out, int ldIn, int M)
{
    __shared__ unsigned short t[64][68];
    const int c0 = blockIdx.x * 64, r0 = blockIdx.y * 64;
    const int lr = threadIdx.x >> 4;
    const int lc = (threadIdx.x & 15) * 4;
#pragma unroll
    for (int i = 0; i < 4; ++i) {
        int row = lr + i * 16;
        float4 v = *(const float4*)&in[(size_t)(r0 + row) * ldIn + c0 + lc];
        ushort4 o;
        o.x = f2bf(v.x); o.y = f2bf(v.y); o.z = f2bf(v.z); o.w = f2bf(v.w);
        *(ushort4*)&t[row][lc] = o;
    }
    __syncthreads();
#pragma unroll
    for (int i = 0; i < 4; ++i) {
        int orow = lr + i * 16;
        ushort4 v;
        v.x = t[lc + 0][orow]; v.y = t[lc + 1][orow];
        v.z = t[lc + 2][orow]; v.w = t[lc + 3][orow];
        *(ushort4*)&out[(size_t)(c0 + orow) * M + r0 + lc] = v;
    }
}

// ---------- 256x256 pipelined GEMM: C[4096,4096] = A * Bt^T (bf16, fp32 acc) ----
// 512 threads / 8 waves (2 m-groups x 4 n-groups). BK=32, ring of 4 LDS buffers
// (128 KiB), prefetch distance 3 K-steps, counted vmcnt(8) once per K-step.
// Per K-step: 4 fine phases; phase p = { ds_read a[2p],a[2p+1] (phase 0 also
// reads the 4 B frags), issue 1 of the 4 stage loads, barrier, 8 MFMA under
// setprio(1) }.  Reads of phase p+1 overlap other waves' phase-p MFMA.
// Buf-overwrite safety: stage(t+3) hits buf[(t-1)&3]; all reads of that buf
// completed (data in regs) before the last barrier of iter t-1, and the DMA
// write returns >~400cy after issue — same discipline as the verified r1 code.
// LDS XOR chunk swizzle: LDS[row][c] holds global[row][c ^ ((row>>1)&3)] (16B
// chunks); reads use chunk = quad ^ ((l16>>1)&3)  -> bank-uniform ds_read_b128.
// MODE 0: fp32 store to Cf.  MODE 1: RoPE+postScale scatter to Ov=[b,h,s,d].
// MODE 2: scatter to Ov = V^T [b,h,d,s].
template <int MODE>
__global__ __launch_bounds__(512, 2) void gemm256(
    const unsigned short* __restrict__ A, const unsigned short* __restrict__ Bt,
    float* __restrict__ Cf, unsigned short* __restrict__ Ov, float postScale)
{
    constexpr int NT = 128;                       // K/32 = 4096/32
    __shared__ unsigned short lA[4][8192];        // 4 bufs x 256 rows x 32 el
    __shared__ unsigned short lB[4][8192];
    const int tid = threadIdx.x;
    const int wave = tid >> 6, lane = tid & 63;
    const int quad = lane >> 4, l16 = lane & 15;
    const int wr = wave >> 2, wc = wave & 3;

    // bijective XCD swizzle (nwg=256, 8 XCDs): same-XCD blocks share A panels
    const int bid = blockIdx.x;
    const int swz = (bid & 7) * 32 + (bid >> 3);
    const int m0 = (swz >> 4) * 256, n0 = (swz & 15) * 256;

    v4f acc[8][4] = {};

    // staging source pointers (pre-swizzled global so LDS dest stays linear)
    const int sr0 = tid >> 2, sc0 = tid & 3;
    const int sr1 = 128 + sr0;
    const unsigned short* pA0 = A  + (size_t)(m0 + sr0) * 4096 + ((sc0 ^ ((sr0 >> 1) & 3)) << 3);
    const unsigned short* pA1 = A  + (size_t)(m0 + sr1) * 4096 + ((sc0 ^ ((sr1 >> 1) & 3)) << 3);
    const unsigned short* pB0 = Bt + (size_t)(n0 + sr0) * 4096 + ((sc0 ^ ((sr0 >> 1) & 3)) << 3);
    const unsigned short* pB1 = Bt + (size_t)(n0 + sr1) * 4096 + ((sc0 ^ ((sr1 >> 1) & 3)) << 3);

    // prologue: 3 K-steps in flight (4 loads per K-step)
    {
        gll16(pA0, &lA[0][tid * 8]);  gll16(pA1, &lA[0][4096 + tid * 8]);
        gll16(pB0, &lB[0][tid * 8]);  gll16(pB1, &lB[0][4096 + tid * 8]);
        gll16(pA0 + 32, &lA[1][tid * 8]);  gll16(pA1 + 32, &lA[1][4096 + tid * 8]);
        gll16(pB0 + 32, &lB[1][tid * 8]);  gll16(pB1 + 32, &lB[1][4096 + tid * 8]);
        gll16(pA0 + 64, &lA[2][tid * 8]);  gll16(pA1 + 64, &lA[2][4096 + tid * 8]);
        gll16(pB0 + 64, &lB[2][tid * 8]);  gll16(pB1 + 64, &lB[2][4096 + tid * 8]);
    }
    asm volatile("s_waitcnt vmcnt(8)" ::: "memory");   // stage(0) landed
    __builtin_amdgcn_s_barrier();

    const int swzk = (l16 >> 1) & 3;
    const int aoff = (wr * 128 + l16) * 32 + ((quad ^ swzk) << 3);
    const int boff = (wc * 16  + l16) * 32 + ((quad ^ swzk) << 3);

#pragma unroll 4
    for (int t = 0; t < NT; ++t) {
        const int cur = t & 3;
        const int nb = (t + 3) & 3;
        const size_t ko = (size_t)(t + 3) << 5;
        const bool pf = (t + 3 < NT);
        const unsigned short* lAc = &lA[cur][0];
        const unsigned short* lBc = &lB[cur][0];
        v8bf b[4], a0, a1;

        // ---- phase 0: B frags(4) + a0,a1; stage A#1; 8 MFMA ----
        b[0] = *(const v8bf*)&lBc[boff];
        b[1] = *(const v8bf*)&lBc[boff + 2048];
        b[2] = *(const v8bf*)&lBc[boff + 4096];
        b[3] = *(const v8bf*)&lBc[boff + 6144];
        a0 = *(const v8bf*)&lAc[aoff];
        a1 = *(const v8bf*)&lAc[aoff + 512];
        if (pf) gll16(pA0 + ko, &lA[nb][tid * 8]);
        __builtin_amdgcn_s_barrier();
        __builtin_amdgcn_s_setprio(1);
#pragma unroll
        for (int ni = 0; ni < 4; ++ni) {
            acc[0][ni] = __builtin_amdgcn_mfma_f32_16x16x32_bf16(a0, b[ni], acc[0][ni], 0, 0, 0);
            acc[1][ni] = __builtin_amdgcn_mfma_f32_16x16x32_bf16(a1, b[ni], acc[1][ni], 0, 0, 0);
        }
        __builtin_amdgcn_s_setprio(0);

        // ---- phase 1: a2,a3; stage A#2; 8 MFMA ----
        a0 = *(const v8bf*)&lAc[aoff + 1024];
        a1 = *(const v8bf*)&lAc[aoff + 1536];
        if (pf) gll16(pA1 + ko, &lA[nb][4096 + tid * 8]);
        __builtin_amdgcn_s_barrier();
        __builtin_amdgcn_s_setprio(1);
#pragma unroll
        for (int ni = 0; ni < 4; ++ni) {
            acc[2][ni] = __builtin_amdgcn_mfma_f32_16x16x32_bf16(a0, b[ni], acc[2][ni], 0, 0, 0);
            acc[3][ni] = __builtin_amdgcn_mfma_f32_16x16x32_bf16(a1, b[ni], acc[3][ni], 0, 0, 0);
        }
        __builtin_amdgcn_s_setprio(0);

        // ---- phase 2: a4,a5; stage B#1; 8 MFMA ----
        a0 = *(const v8bf*)&lAc[aoff + 2048];
        a1 = *(const v8bf*)&lAc[aoff + 2560];
        if (pf) gll16(pB0 + ko, &lB[nb][tid * 8]);
        __builtin_amdgcn_s_barrier();
        __builtin_amdgcn_s_setprio(1);
#pragma unroll
        for (int ni = 0; ni < 4; ++ni) {
            acc[4][ni] = __builtin_amdgcn_mfma_f32_16x16x32_bf16(a0, b[ni], acc[4][ni], 0, 0, 0);
            acc[5][ni] = __builtin_amdgcn_mfma_f32_16x16x32_bf16(a1, b[ni], acc[5][ni], 0, 0, 0);
        }
        __builtin_amdgcn_s_setprio(0);

        // ---- phase 3: a6,a7; stage B#2; counted vmcnt gate; 8 MFMA ----
        a0 = *(const v8bf*)&lAc[aoff + 3072];
        a1 = *(const v8bf*)&lAc[aoff + 3584];
        if (pf) gll16(pB1 + ko, &lB[nb][4096 + tid * 8]);
        // gate: stage(t+1) fully landed (newest 8 = stages t+2, t+3)
        if (t < NT - 3)       asm volatile("s_waitcnt vmcnt(8)" ::: "memory");
        else if (t == NT - 3) asm volatile("s_waitcnt vmcnt(4)" ::: "memory");
        else if (t == NT - 2) asm volatile("s_waitcnt vmcnt(0)" ::: "memory");
        __builtin_amdgcn_s_barrier();
        __builtin_amdgcn_s_setprio(1);
#pragma unroll
        for (int ni = 0; ni < 4; ++ni) {
            acc[6][ni] = __builtin_amdgcn_mfma_f32_16x16x32_bf16(a0, b[ni], acc[6][ni], 0, 0, 0);
            acc[7][ni] = __builtin_amdgcn_mfma_f32_16x16x32_bf16(a1, b[ni], acc[7][ni], 0, 0, 0);
        }
        __builtin_amdgcn_s_setprio(0);
    }

    // ---- epilogue; D layout: row(m) = quad*4+r, col(n) = l16 ----
    if (MODE == 0) {
#pragma unroll
        for (int mi = 0; mi < 8; ++mi) {
            int gm = m0 + wr * 128 + mi * 16 + quad * 4;
#pragma unroll
            for (int ni = 0; ni < 4; ++ni) {
                int gn = n0 + ni * 64 + wc * 16 + l16;
#pragma unroll
                for (int r = 0; r < 4; ++r)
                    Cf[(size_t)(gm + r) * 4096 + gn] = acc[mi][ni][r];
            }
        }
    } else if (MODE == 1) {
        // RoPE: pairs (d1, d1+64) = (acc[mi][2h], acc[mi][2h+1]) same lane
        const int d1 = wc * 16 + l16;                  // 0..63
        const float inv = powf(10000.0f, -(float)d1 * 0.015625f);
        const int head0 = n0 >> 7;                     // 2 heads per 256-n block
#pragma unroll
        for (int mi = 0; mi < 8; ++mi) {
            int gmb = m0 + wr * 128 + mi * 16 + quad * 4;
            int b = gmb >> 11, sb = gmb & 2047;
            float sn[4], cs[4];
#pragma unroll
            for (int r = 0; r < 4; ++r)
                sincosf((float)(sb + r) * inv, &sn[r], &cs[r]);
#pragma unroll
            for (int hd = 0; hd < 2; ++hd) {
                size_t hb = ((size_t)(b * 32 + head0 + hd)) << 11;
#pragma unroll
                for (int r = 0; r < 4; ++r) {
                    float x1 = acc[mi][2 * hd][r], x2 = acc[mi][2 * hd + 1][r];
                    size_t adr = (hb + sb + r) << 7;
                    Ov[adr + d1]      = f2bf((x1 * cs[r] - x2 * sn[r]) * postScale);
                    Ov[adr + d1 + 64] = f2bf((x2 * cs[r] + x1 * sn[r]) * postScale);
                }
            }
        }
    } else {
        // V^T: Ov[bh][d][s], s contiguous -> pack 4 rows as ushort4
        const int head0 = n0 >> 7;
#pragma unroll
        for (int mi = 0; mi < 8; ++mi) {
            int gmb = m0 + wr * 128 + mi * 16 + quad * 4;
            int b = gmb >> 11, s0 = gmb & 2047;
#pragma unroll
            for (int ni = 0; ni < 4; ++ni) {
                int head = head0 + (ni >> 1);
                int d = ((ni & 1) << 6) + wc * 16 + l16;
                ushort4 o;
                o.x = f2bf(acc[mi][ni][0]); o.y = f2bf(acc[mi][ni][1]);
                o.z = f2bf(acc[mi][ni][2]); o.w = f2bf(acc[mi][ni][3]);
                *(ushort4*)&Ov[(((size_t)(b * 32 + head)) << 18) +
                               ((size_t)d << 11) + s0] = o;
            }
        }
    }
}

// ---------- causal flash attention, swapped-operand / in-register P ----------
// KVBLK=32 dbuf, 5 blocks/CU.  This round: defer-max (T13, skip O-rescale when
// no lane's tile-max exceeds running max + 6/log2e; P bounded by 2^6, bf16-safe)
// and setprio(1) around both MFMA clusters (T5).
__global__ __launch_bounds__(256, 5) void attn_kernel(
    const unsigned short* __restrict__ Q, const unsigned short* __restrict__ Kg,
    const unsigned short* __restrict__ Vt, unsigned short* __restrict__ ctx)
{
    __shared__ unsigned short lK[2][32 * 128];
    __shared__ unsigned short lV[2][128 * 32];

    const int qt  = gridDim.x - 1 - blockIdx.x;
    const int bh  = blockIdx.y;
    const int tid = threadIdx.x;
    const int wave = tid >> 6, lane = tid & 63;
    const int quad = lane >> 4, l16 = lane & 15;
    const int q0 = qt * 64;
    const size_t base = (size_t)bh << 18;

    auto stage = [&](int kv0, int buf) {
#pragma unroll
        for (int it = 0; it < 2; ++it) {
            int cid = it * 256 + tid;
            int row = cid >> 4, chk = cid & 15;
            gll16(Kg + base + ((size_t)(kv0 + row) << 7) + ((chk ^ (row & 15)) << 3),
                  &lK[buf][cid << 3]);
        }
#pragma unroll
        for (int it = 0; it < 2; ++it) {
            int cid = it * 256 + tid;
            int row = cid >> 2, chk = cid & 3;
            gll16(Vt + base + ((size_t)row << 11) + kv0 + ((chk ^ ((row >> 1) & 3)) << 3),
                  &lV[buf][cid << 3]);
        }
    };

    v8bf qf[4];
    {
        const unsigned short* qrow =
            Q + base + ((size_t)(q0 + wave * 16 + l16) << 7) + quad * 8;
#pragma unroll
        for (int kc = 0; kc < 4; ++kc)
            qf[kc] = *(const v8bf*)(qrow + kc * 32);
    }

    const int qg = q0 + wave * 16 + l16;
    float mrow = -1e30f, lrow = 0.f;
    v4f Oa[8] = {};
    const float c2 = 1.4426950408889634f;
    const float thr = 4.1589045f;                // 6 / log2(e): P <= 2^6

    const int nkt = 2 * qt + 2;
    stage(0, 0);
    for (int kt = 0; kt < nkt; ++kt) {
        const int cur = kt & 1;
        __syncthreads();
        if (kt + 1 < nkt) stage((kt + 1) * 32, cur ^ 1);

        const unsigned short* K_ = &lK[cur][0];
        const unsigned short* V_ = &lV[cur][0];
        const int kv0 = kt * 32;

        v4f sc[2] = {};
        __builtin_amdgcn_s_setprio(1);
#pragma unroll
        for (int kc = 0; kc < 4; ++kc) {
#pragma unroll
            for (int nt = 0; nt < 2; ++nt) {
                v8bf kf = *(const v8bf*)&K_[((nt * 16 + l16) << 7) +
                                            ((((kc << 2) + quad) ^ l16) << 3)];
                sc[nt] = __builtin_amdgcn_mfma_f32_16x16x32_bf16(kf, qf[kc], sc[nt], 0, 0, 0);
            }
        }
        __builtin_amdgcn_s_setprio(0);

        if (kt >= nkt - 2) {
#pragma unroll
            for (int nt = 0; nt < 2; ++nt) {
                int kvb = kv0 + nt * 16 + quad * 4;
#pragma unroll
                for (int r = 0; r < 4; ++r)
                    if (kvb + r > qg) sc[nt][r] = -1e30f;
            }
        }

        float tmax = fmaxf(fmaxf(fmaxf(sc[0][0], sc[0][1]), fmaxf(sc[0][2], sc[0][3])),
                           fmaxf(fmaxf(sc[1][0], sc[1][1]), fmaxf(sc[1][2], sc[1][3])));
        tmax = fmaxf(tmax, __shfl_xor(tmax, 16));
        tmax = fmaxf(tmax, __shfl_xor(tmax, 32));

        // defer-max: only rescale when some lane's max actually grew past thr
        if (__ballot(tmax > mrow + thr) != 0ull) {
            float mnew = fmaxf(mrow, tmax);
            float alpha = exp2f((mrow - mnew) * c2);
            mrow = mnew;
            lrow *= alpha;
#pragma unroll
            for (int d8 = 0; d8 < 8; ++d8)
#pragma unroll
                for (int r = 0; r < 4; ++r)
                    Oa[d8][r] *= alpha;
        }
        const float mc = mrow * c2;
        float rsum = 0.f;
#pragma unroll
        for (int nt = 0; nt < 2; ++nt)
#pragma unroll
            for (int r = 0; r < 4; ++r) {
                float p = exp2f(fmaf(sc[nt][r], c2, -mc));
                sc[nt][r] = p;
                rsum += p;
            }
        rsum += __shfl_xor(rsum, 16);
        rsum += __shfl_xor(rsum, 32);
        lrow += rsum;

        unsigned int pk0[2], pk1[2];
#pragma unroll
        for (int h = 0; h < 2; ++h) {
            pk0[h] = (unsigned int)f2bf(sc[0][2 * h]) |
                     ((unsigned int)f2bf(sc[0][2 * h + 1]) << 16);
            pk1[h] = (unsigned int)f2bf(sc[1][2 * h]) |
                     ((unsigned int)f2bf(sc[1][2 * h + 1]) << 16);
        }
        union { unsigned int u[4]; v8bf v; } pu;
        const int sbase = ((quad & 1) << 5) + l16;
#pragma unroll
        for (int j2 = 0; j2 < 4; ++j2) {
            int src = sbase + ((j2 >> 1) << 4);
            int a = __shfl((int)pk0[j2 & 1], src);
            int b = __shfl((int)pk1[j2 & 1], src);
            pu.u[j2] = (quad < 2) ? (unsigned int)a : (unsigned int)b;
        }
        v8bf pf = pu.v;

        __builtin_amdgcn_s_setprio(1);
#pragma unroll
        for (int dt = 0; dt < 8; ++dt) {
            v8bf vf = *(const v8bf*)&V_[((dt * 16 + l16) << 5) +
                                        ((quad ^ ((l16 >> 1) & 3)) << 3)];
            Oa[dt] = __builtin_amdgcn_mfma_f32_16x16x32_bf16(vf, pf, Oa[dt], 0, 0, 0);
        }
        __builtin_amdgcn_s_setprio(0);
    }

    const int b = bh >> 5, h = bh & 31;
    const float invl = 1.0f / lrow;
    size_t rowb = ((size_t)(b * 2048 + qg) << 12) + ((size_t)h << 7);
#pragma unroll
    for (int dt = 0; dt < 8; ++dt) {
        ushort4 o;
        o.x = f2bf(Oa[dt][0] * invl);
        o.y = f2bf(Oa[dt][1] * invl);
        o.z = f2bf(Oa[dt][2] * invl);
        o.w = f2bf(Oa[dt][3] * invl);
        *(ushort4*)&ctx[rowb + dt * 16 + quad * 4] = o;
    }
}

// ---------- launch ----------
extern "C" void kernel_launch(void* const* d_in, const int* in_sizes, int n_in,
                              void* d_out, int out_size, void* d_ws, size_t ws_size,
                              hipStream_t stream)
{
    const float* x    = (const float*)d_in[0];   // (2,2048,4096) fp32
    const float* Wqkv = (const float*)d_in[1];   // (4096,12288)  fp32
    const float* Wo   = (const float*)d_in[2];   // (4096,4096)   fp32
    float* out = (float*)d_out;                  // (2,2048,4096) fp32

    char* ws = (char*)d_ws;
    const size_t B32 = (size_t)32 * 1024 * 1024;
    unsigned short* B0 = (unsigned short*)(ws);              // xb, later ctx
    unsigned short* B1 = (unsigned short*)(ws + 1 * B32);    // Q (pre-scaled, roped)
    unsigned short* B2 = (unsigned short*)(ws + 2 * B32);    // K (roped)
    unsigned short* B3 = (unsigned short*)(ws + 3 * B32);    // V^T
    unsigned short* B4 = (unsigned short*)(ws + 4 * B32);    // weight chunk / Wo^T

    const float qscale = 0.08838834764831845f;   // 1/sqrt(128)

    // 1. x -> bf16
    cvt_f32_bf16<<<16384, 256, 0, stream>>>(x, B0);
    // 2. chunk 0: Q = rope(x*Wq) * qscale  -> B1 [b,h,s,d]
    transpose_f32_bf16<<<dim3(64, 64), 256, 0, stream>>>(Wqkv, B4, 12288, 4096);
    gemm256<1><<<256, 512, 0, stream>>>(B0, B4, nullptr, B1, qscale);
    // 3. chunk 1: K = rope(x*Wk) -> B2 [b,h,s,d]
    transpose_f32_bf16<<<dim3(64, 64), 256, 0, stream>>>(Wqkv + 4096, B4, 12288, 4096);
    gemm256<1><<<256, 512, 0, stream>>>(B0, B4, nullptr, B2, 1.0f);
    // 4. chunk 2: V^T = (x*Wv)^T -> B3 [b,h,d,s]
    transpose_f32_bf16<<<dim3(64, 64), 256, 0, stream>>>(Wqkv + 8192, B4, 12288, 4096);
    gemm256<2><<<256, 512, 0, stream>>>(B0, B4, nullptr, B3, 1.0f);
    // 5. Wo^T -> B4
    transpose_f32_bf16<<<dim3(64, 64), 256, 0, stream>>>(Wo, B4, 4096, 4096);
    // 6. flash attention -> ctx (B0; xb dead after chunk GEMMs)
    attn_kernel<<<dim3(32, 64), 256, 0, stream>>>(B1, B2, B3, B0);
    // 7. output projection: ctx * Wo -> fp32 out
    gemm256<0><<<256, 512, 0, stream>>>(B0, B4, out, nullptr, 1.0f);
}

// Round 4
// 1065.993 us; speedup vs baseline: 1.4161x; 1.0126x over previous
//
#include <hip/hip_runtime.h>

// ---------- types & helpers ----------
typedef __bf16 v8bf __attribute__((ext_vector_type(8)));
typedef float  v4f  __attribute__((ext_vector_type(4)));

__device__ __forceinline__ float bf2f(unsigned short h) {
    union { unsigned int u; float f; } x; x.u = ((unsigned int)h) << 16; return x.f;
}
__device__ __forceinline__ unsigned short f2bf(float f) {
    union { float f; unsigned int u; } x; x.f = f;
    unsigned int u = x.u;
    u += 0x7fffu + ((u >> 16) & 1u);           // RNE
    return (unsigned short)(u >> 16);
}
// async global->LDS, 16B per lane. LDS dest must be wave-uniform base + lane*16.
__device__ __forceinline__ void gll16(const void* g, void* l) {
    __builtin_amdgcn_global_load_lds((__attribute__((address_space(1))) void*)g,
                                     (__attribute__((address_space(3))) void*)l,
                                     16, 0, 0);
}

// ---------- fp32 -> bf16 elementwise convert (x) ----------
__global__ __launch_bounds__(256) void cvt_f32_bf16(
    const float* __restrict__ in, unsigned short* __restrict__ out)
{
    size_t i = ((size_t)blockIdx.x * 256 + threadIdx.x) * 4;
    float4 v = *(const float4*)&in[i];
    ushort4 o;
    o.x = f2bf(v.x); o.y = f2bf(v.y); o.z = f2bf(v.z); o.w = f2bf(v.w);
    *(ushort4*)&out[i] = o;
}

// ---------- fp32 -> bf16 transposing convert (weights), 64x64 tiles ----------
__global__ __launch_bounds__(256) void transpose_f32_bf16(
    const float* __restrict__ in, unsigned short* __restrict__ out, int ldIn, int M)
{
    __shared__ unsigned short t[64][68];
    const int c0 = blockIdx.x * 64, r0 = blockIdx.y * 64;
    const int lr = threadIdx.x >> 4;
    const int lc = (threadIdx.x & 15) * 4;
#pragma unroll
    for (int i = 0; i < 4; ++i) {
        int row = lr + i * 16;
        float4 v = *(const float4*)&in[(size_t)(r0 + row) * ldIn + c0 + lc];
        ushort4 o;
        o.x = f2bf(v.x); o.y = f2bf(v.y); o.z = f2bf(v.z); o.w = f2bf(v.w);
        *(ushort4*)&t[row][lc] = o;
    }
    __syncthreads();
#pragma unroll
    for (int i = 0; i < 4; ++i) {
        int orow = lr + i * 16;
        ushort4 v;
        v.x = t[lc + 0][orow]; v.y = t[lc + 1][orow];
        v.z = t[lc + 2][orow]; v.w = t[lc + 3][orow];
        *(ushort4*)&out[(size_t)(c0 + orow) * M + r0 + lc] = v;
    }
}

// ---------- 256x256 GEMM, m201-style 8-phase schedule ----------
// C[4096,4096] = A[4096,4096] * Bt[4096,4096]^T, bf16 in, fp32 acc.
// 512 threads / 8 waves (wr = m-group 0..1, wc = n-group 0..3); wave tile
// 128(m) x 64(n) with n interleaved as ni*64 + wc*16 (RoPE pairs lane-local).
// BK=64; LDS = 2 dbuf x 2 half x 128x64 x (A,B) = 128 KiB.
// Per K-tile: 4 phases (Gray quadrants (mh,nh) = 00,01,11,10), each phase =
// { ds_read quadrant frags ; stage ONE half-tile (2 gll16) ; barrier ;
//   setprio(1) 16 MFMA setprio(0) ; barrier }.  b0 kept in regs -> phase 3
// has zero ds_reads.  ONE counted vmcnt(6) per K-tile (3 half-tiles in
// flight), never 0 in steady state.
// Stage schedule (into freed halves): t.p0: A1(t+1) [A halves of buf^1 free
// since (t-1).p2]; t.p1: B0(t+2) [B0 free after p0]; t.p2: B1(t+2) [free
// after p1]; t.p3: A0(t+2) [A free after p2].  Gate at t.p3 ensures K-tile
// t+1 fully landed before (t+1).p0 reads it.
// LDS chunk swizzle: LDS[row][c] = global[row][c ^ (row&7)] (16B chunks);
// reads use chunk (kc*4+quad)^(l16&7) -> full-bank-coverage ds_read_b128.
template <int MODE>
__global__ __launch_bounds__(512, 2) void gemm256(
    const unsigned short* __restrict__ A, const unsigned short* __restrict__ Bt,
    float* __restrict__ Cf, unsigned short* __restrict__ Ov, float postScale)
{
    constexpr int NT = 64;                        // K / 64
    __shared__ unsigned short lA[4 * 8192];       // [buf][half][128 rows x 64 el]
    __shared__ unsigned short lB[4 * 8192];
    const int tid = threadIdx.x;
    const int wave = tid >> 6, lane = tid & 63;
    const int quad = lane >> 4, l16 = lane & 15;
    const int wr = wave >> 2, wc = wave & 3;

    // bijective XCD swizzle (nwg=256, 8 XCDs): same-XCD blocks share A panels
    const int bid = blockIdx.x;
    const int swz = (bid & 7) * 32 + (bid >> 3);
    const int m0 = (swz >> 4) * 256, n0 = (swz & 15) * 256;

    v4f acc[8][4] = {};

    // ---- staging setup (source pre-swizzled; LDS dest lane-linear) ----
    const int srow = tid >> 3;                          // 0..63
    const int sof  = ((tid & 7) ^ (srow & 7)) << 3;     // swizzled src chunk
    const unsigned short* pA[2][2]; const unsigned short* pB[2][2];
#pragma unroll
    for (int H = 0; H < 2; ++H)
#pragma unroll
        for (int i = 0; i < 2; ++i) {
            pA[H][i] = A  + (size_t)(m0 + H * 128 + i * 64 + srow) * 4096 + sof;
            pB[H][i] = Bt + (size_t)(n0 + H * 128 + i * 64 + srow) * 4096 + sof;
        }
    const int dst0 = tid * 8;

    auto stA = [&](int H, int kt) {
        unsigned short* d = &lA[((kt & 1) * 2 + H) * 8192 + dst0];
        gll16(pA[H][0] + kt * 64, d);
        gll16(pA[H][1] + kt * 64, d + 4096);
    };
    auto stB = [&](int H, int kt) {
        unsigned short* d = &lB[((kt & 1) * 2 + H) * 8192 + dst0];
        gll16(pB[H][0] + kt * 64, d);
        gll16(pB[H][1] + kt * 64, d + 4096);
    };

    // prologue: K-tile 0 (4 halves) + K-tile 1 {B0,B1,A0}; A1(1) staged at t=0.p0
    stB(0, 0); stB(1, 0); stA(0, 0); stA(1, 0);
    stB(0, 1); stB(1, 1); stA(0, 1);
    asm volatile("s_waitcnt vmcnt(6)" ::: "memory");    // K-tile 0 landed
    __builtin_amdgcn_s_barrier();

    const int cko0 = (quad ^ (l16 & 7)) << 3;           // kc=0 chunk
    const int cko1 = ((4 + quad) ^ (l16 & 7)) << 3;     // kc=1 chunk
    const int arow0 = l16 * 64;
    const int brow0 = (wc * 16 + l16) * 64;

#pragma unroll 2
    for (int t = 0; t < NT; ++t) {
        const int c = t & 1;
        const unsigned short* lAc = &lA[(c * 2 + wr) * 8192];
        const unsigned short* lB0 = &lB[(c * 2 + 0) * 8192];
        const unsigned short* lB1 = &lB[(c * 2 + 1) * 8192];
        v8bf a[4][2], b0[2][2], b1[2][2];

        // -------- phase 0: (mh0, nh0)  mi 0-3 x ni 0-1 --------
#pragma unroll
        for (int mi = 0; mi < 4; ++mi) {
            a[mi][0] = *(const v8bf*)&lAc[arow0 + mi * 1024 + cko0];
            a[mi][1] = *(const v8bf*)&lAc[arow0 + mi * 1024 + cko1];
        }
#pragma unroll
        for (int ni = 0; ni < 2; ++ni) {
            b0[ni][0] = *(const v8bf*)&lB0[brow0 + ni * 4096 + cko0];
            b0[ni][1] = *(const v8bf*)&lB0[brow0 + ni * 4096 + cko1];
        }
        if (t + 1 < NT) stA(1, t + 1);
        __builtin_amdgcn_s_barrier();
        __builtin_amdgcn_s_setprio(1);
#pragma unroll
        for (int kc = 0; kc < 2; ++kc)
#pragma unroll
            for (int mi = 0; mi < 4; ++mi)
#pragma unroll
                for (int ni = 0; ni < 2; ++ni)
                    acc[mi][ni] = __builtin_amdgcn_mfma_f32_16x16x32_bf16(
                        a[mi][kc], b0[ni][kc], acc[mi][ni], 0, 0, 0);
        __builtin_amdgcn_s_setprio(0);
        __builtin_amdgcn_s_barrier();

        // -------- phase 1: (mh0, nh1)  mi 0-3 x ni 2-3 --------
#pragma unroll
        for (int ni = 0; ni < 2; ++ni) {
            b1[ni][0] = *(const v8bf*)&lB1[brow0 + ni * 4096 + cko0];
            b1[ni][1] = *(const v8bf*)&lB1[brow0 + ni * 4096 + cko1];
        }
        if (t + 2 < NT) stB(0, t + 2);
        __builtin_amdgcn_s_barrier();
        __builtin_amdgcn_s_setprio(1);
#pragma unroll
        for (int kc = 0; kc < 2; ++kc)
#pragma unroll
            for (int mi = 0; mi < 4; ++mi)
#pragma unroll
                for (int ni = 0; ni < 2; ++ni)
                    acc[mi][2 + ni] = __builtin_amdgcn_mfma_f32_16x16x32_bf16(
                        a[mi][kc], b1[ni][kc], acc[mi][2 + ni], 0, 0, 0);
        __builtin_amdgcn_s_setprio(0);
        __builtin_amdgcn_s_barrier();

        // -------- phase 2: (mh1, nh1)  mi 4-7 x ni 2-3 --------
#pragma unroll
        for (int mi = 0; mi < 4; ++mi) {
            a[mi][0] = *(const v8bf*)&lAc[arow0 + (4 + mi) * 1024 + cko0];
            a[mi][1] = *(const v8bf*)&lAc[arow0 + (4 + mi) * 1024 + cko1];
        }
        if (t + 2 < NT) stB(1, t + 2);
        __builtin_amdgcn_s_barrier();
        __builtin_amdgcn_s_setprio(1);
#pragma unroll
        for (int kc = 0; kc < 2; ++kc)
#pragma unroll
            for (int mi = 0; mi < 4; ++mi)
#pragma unroll
                for (int ni = 0; ni < 2; ++ni)
                    acc[4 + mi][2 + ni] = __builtin_amdgcn_mfma_f32_16x16x32_bf16(
                        a[mi][kc], b1[ni][kc], acc[4 + mi][2 + ni], 0, 0, 0);
        __builtin_amdgcn_s_setprio(0);
        __builtin_amdgcn_s_barrier();

        // -------- phase 3: (mh1, nh0)  mi 4-7 x ni 0-1 (b0 from regs) --------
        if (t + 2 < NT) {
            stA(0, t + 2);
            asm volatile("s_waitcnt vmcnt(6)" ::: "memory");   // K-tile t+1 landed
        } else if (t + 1 < NT) {
            asm volatile("s_waitcnt vmcnt(0)" ::: "memory");
        }
        __builtin_amdgcn_s_barrier();
        __builtin_amdgcn_s_setprio(1);
#pragma unroll
        for (int kc = 0; kc < 2; ++kc)
#pragma unroll
            for (int mi = 0; mi < 4; ++mi)
#pragma unroll
                for (int ni = 0; ni < 2; ++ni)
                    acc[4 + mi][ni] = __builtin_amdgcn_mfma_f32_16x16x32_bf16(
                        a[mi][kc], b0[ni][kc], acc[4 + mi][ni], 0, 0, 0);
        __builtin_amdgcn_s_setprio(0);
        __builtin_amdgcn_s_barrier();
    }

    // ---- epilogue; D layout: row(m) = quad*4 + r, col(n) = l16 ----
    if (MODE == 0) {
#pragma unroll
        for (int mi = 0; mi < 8; ++mi) {
            int gm = m0 + wr * 128 + mi * 16 + quad * 4;
#pragma unroll
            for (int ni = 0; ni < 4; ++ni) {
                int gn = n0 + ni * 64 + wc * 16 + l16;
#pragma unroll
                for (int r = 0; r < 4; ++r)
                    Cf[(size_t)(gm + r) * 4096 + gn] = acc[mi][ni][r];
            }
        }
    } else if (MODE == 1) {
        // RoPE: pairs (d1, d1+64) = (acc[mi][2h], acc[mi][2h+1]) same lane
        const int d1 = wc * 16 + l16;                  // 0..63
        const float inv = powf(10000.0f, -(float)d1 * 0.015625f);
        const int head0 = n0 >> 7;                     // 2 heads per 256-n block
#pragma unroll
        for (int mi = 0; mi < 8; ++mi) {
            int gmb = m0 + wr * 128 + mi * 16 + quad * 4;
            int b = gmb >> 11, sb = gmb & 2047;
            float sn[4], cs[4];
#pragma unroll
            for (int r = 0; r < 4; ++r)
                sincosf((float)(sb + r) * inv, &sn[r], &cs[r]);
#pragma unroll
            for (int hd = 0; hd < 2; ++hd) {
                size_t hb = ((size_t)(b * 32 + head0 + hd)) << 11;
#pragma unroll
                for (int r = 0; r < 4; ++r) {
                    float x1 = acc[mi][2 * hd][r], x2 = acc[mi][2 * hd + 1][r];
                    size_t adr = (hb + sb + r) << 7;
                    Ov[adr + d1]      = f2bf((x1 * cs[r] - x2 * sn[r]) * postScale);
                    Ov[adr + d1 + 64] = f2bf((x2 * cs[r] + x1 * sn[r]) * postScale);
                }
            }
        }
    } else {
        // V^T: Ov[bh][d][s], s contiguous -> pack 4 rows as ushort4
        const int head0 = n0 >> 7;
#pragma unroll
        for (int mi = 0; mi < 8; ++mi) {
            int gmb = m0 + wr * 128 + mi * 16 + quad * 4;
            int b = gmb >> 11, s0 = gmb & 2047;
#pragma unroll
            for (int ni = 0; ni < 4; ++ni) {
                int head = head0 + (ni >> 1);
                int d = ((ni & 1) << 6) + wc * 16 + l16;
                ushort4 o;
                o.x = f2bf(acc[mi][ni][0]); o.y = f2bf(acc[mi][ni][1]);
                o.z = f2bf(acc[mi][ni][2]); o.w = f2bf(acc[mi][ni][3]);
                *(ushort4*)&Ov[(((size_t)(b * 32 + head)) << 18) +
                               ((size_t)d << 11) + s0] = o;
            }
        }
    }
}

// ---------- causal flash attention, swapped-operand / in-register P ----------
// KVBLK=32 dbuf, 5 blocks/CU; defer-max (T13) + setprio around MFMA (T5).
__global__ __launch_bounds__(256, 5) void attn_kernel(
    const unsigned short* __restrict__ Q, const unsigned short* __restrict__ Kg,
    const unsigned short* __restrict__ Vt, unsigned short* __restrict__ ctx)
{
    __shared__ unsigned short lK[2][32 * 128];
    __shared__ unsigned short lV[2][128 * 32];

    const int qt  = gridDim.x - 1 - blockIdx.x;
    const int bh  = blockIdx.y;
    const int tid = threadIdx.x;
    const int wave = tid >> 6, lane = tid & 63;
    const int quad = lane >> 4, l16 = lane & 15;
    const int q0 = qt * 64;
    const size_t base = (size_t)bh << 18;

    auto stage = [&](int kv0, int buf) {
#pragma unroll
        for (int it = 0; it < 2; ++it) {
            int cid = it * 256 + tid;
            int row = cid >> 4, chk = cid & 15;
            gll16(Kg + base + ((size_t)(kv0 + row) << 7) + ((chk ^ (row & 15)) << 3),
                  &lK[buf][cid << 3]);
        }
#pragma unroll
        for (int it = 0; it < 2; ++it) {
            int cid = it * 256 + tid;
            int row = cid >> 2, chk = cid & 3;
            gll16(Vt + base + ((size_t)row << 11) + kv0 + ((chk ^ ((row >> 1) & 3)) << 3),
                  &lV[buf][cid << 3]);
        }
    };

    v8bf qf[4];
    {
        const unsigned short* qrow =
            Q + base + ((size_t)(q0 + wave * 16 + l16) << 7) + quad * 8;
#pragma unroll
        for (int kc = 0; kc < 4; ++kc)
            qf[kc] = *(const v8bf*)(qrow + kc * 32);
    }

    const int qg = q0 + wave * 16 + l16;
    float mrow = -1e30f, lrow = 0.f;
    v4f Oa[8] = {};
    const float c2 = 1.4426950408889634f;
    const float thr = 4.1589045f;                // 6 / log2(e): P <= 2^6

    const int nkt = 2 * qt + 2;
    stage(0, 0);
    for (int kt = 0; kt < nkt; ++kt) {
        const int cur = kt & 1;
        __syncthreads();
        if (kt + 1 < nkt) stage((kt + 1) * 32, cur ^ 1);

        const unsigned short* K_ = &lK[cur][0];
        const unsigned short* V_ = &lV[cur][0];
        const int kv0 = kt * 32;

        v4f sc[2] = {};
        __builtin_amdgcn_s_setprio(1);
#pragma unroll
        for (int kc = 0; kc < 4; ++kc) {
#pragma unroll
            for (int nt = 0; nt < 2; ++nt) {
                v8bf kf = *(const v8bf*)&K_[((nt * 16 + l16) << 7) +
                                            ((((kc << 2) + quad) ^ l16) << 3)];
                sc[nt] = __builtin_amdgcn_mfma_f32_16x16x32_bf16(kf, qf[kc], sc[nt], 0, 0, 0);
            }
        }
        __builtin_amdgcn_s_setprio(0);

        if (kt >= nkt - 2) {
#pragma unroll
            for (int nt = 0; nt < 2; ++nt) {
                int kvb = kv0 + nt * 16 + quad * 4;
#pragma unroll
                for (int r = 0; r < 4; ++r)
                    if (kvb + r > qg) sc[nt][r] = -1e30f;
            }
        }

        float tmax = fmaxf(fmaxf(fmaxf(sc[0][0], sc[0][1]), fmaxf(sc[0][2], sc[0][3])),
                           fmaxf(fmaxf(sc[1][0], sc[1][1]), fmaxf(sc[1][2], sc[1][3])));
        tmax = fmaxf(tmax, __shfl_xor(tmax, 16));
        tmax = fmaxf(tmax, __shfl_xor(tmax, 32));

        // defer-max: only rescale when some lane's max actually grew past thr
        if (__ballot(tmax > mrow + thr) != 0ull) {
            float mnew = fmaxf(mrow, tmax);
            float alpha = exp2f((mrow - mnew) * c2);
            mrow = mnew;
            lrow *= alpha;
#pragma unroll
            for (int d8 = 0; d8 < 8; ++d8)
#pragma unroll
                for (int r = 0; r < 4; ++r)
                    Oa[d8][r] *= alpha;
        }
        const float mc = mrow * c2;
        float rsum = 0.f;
#pragma unroll
        for (int nt = 0; nt < 2; ++nt)
#pragma unroll
            for (int r = 0; r < 4; ++r) {
                float p = exp2f(fmaf(sc[nt][r], c2, -mc));
                sc[nt][r] = p;
                rsum += p;
            }
        rsum += __shfl_xor(rsum, 16);
        rsum += __shfl_xor(rsum, 32);
        lrow += rsum;

        unsigned int pk0[2], pk1[2];
#pragma unroll
        for (int h = 0; h < 2; ++h) {
            pk0[h] = (unsigned int)f2bf(sc[0][2 * h]) |
                     ((unsigned int)f2bf(sc[0][2 * h + 1]) << 16);
            pk1[h] = (unsigned int)f2bf(sc[1][2 * h]) |
                     ((unsigned int)f2bf(sc[1][2 * h + 1]) << 16);
        }
        union { unsigned int u[4]; v8bf v; } pu;
        const int sbase = ((quad & 1) << 5) + l16;
#pragma unroll
        for (int j2 = 0; j2 < 4; ++j2) {
            int src = sbase + ((j2 >> 1) << 4);
            int a = __shfl((int)pk0[j2 & 1], src);
            int b = __shfl((int)pk1[j2 & 1], src);
            pu.u[j2] = (quad < 2) ? (unsigned int)a : (unsigned int)b;
        }
        v8bf pf = pu.v;

        __builtin_amdgcn_s_setprio(1);
#pragma unroll
        for (int dt = 0; dt < 8; ++dt) {
            v8bf vf = *(const v8bf*)&V_[((dt * 16 + l16) << 5) +
                                        ((quad ^ ((l16 >> 1) & 3)) << 3)];
            Oa[dt] = __builtin_amdgcn_mfma_f32_16x16x32_bf16(vf, pf, Oa[dt], 0, 0, 0);
        }
        __builtin_amdgcn_s_setprio(0);
    }

    const int b = bh >> 5, h = bh & 31;
    const float invl = 1.0f / lrow;
    size_t rowb = ((size_t)(b * 2048 + qg) << 12) + ((size_t)h << 7);
#pragma unroll
    for (int dt = 0; dt < 8; ++dt) {
        ushort4 o;
        o.x = f2bf(Oa[dt][0] * invl);
        o.y = f2bf(Oa[dt][1] * invl);
        o.z = f2bf(Oa[dt][2] * invl);
        o.w = f2bf(Oa[dt][3] * invl);
        *(ushort4*)&ctx[rowb + dt * 16 + quad * 4] = o;
    }
}

// ---------- launch ----------
extern "C" void kernel_launch(void* const* d_in, const int* in_sizes, int n_in,
                              void* d_out, int out_size, void* d_ws, size_t ws_size,
                              hipStream_t stream)
{
    const float* x    = (const float*)d_in[0];   // (2,2048,4096) fp32
    const float* Wqkv = (const float*)d_in[1];   // (4096,12288)  fp32
    const float* Wo   = (const float*)d_in[2];   // (4096,4096)   fp32
    float* out = (float*)d_out;                  // (2,2048,4096) fp32

    char* ws = (char*)d_ws;
    const size_t B32 = (size_t)32 * 1024 * 1024;
    unsigned short* B0 = (unsigned short*)(ws);              // xb, later ctx
    unsigned short* B1 = (unsigned short*)(ws + 1 * B32);    // Q (pre-scaled, roped)
    unsigned short* B2 = (unsigned short*)(ws + 2 * B32);    // K (roped)
    unsigned short* B3 = (unsigned short*)(ws + 3 * B32);    // V^T
    unsigned short* B4 = (unsigned short*)(ws + 4 * B32);    // weight chunk / Wo^T

    const float qscale = 0.08838834764831845f;   // 1/sqrt(128)

    // 1. x -> bf16
    cvt_f32_bf16<<<16384, 256, 0, stream>>>(x, B0);
    // 2. chunk 0: Q = rope(x*Wq) * qscale  -> B1 [b,h,s,d]
    transpose_f32_bf16<<<dim3(64, 64), 256, 0, stream>>>(Wqkv, B4, 12288, 4096);
    gemm256<1><<<256, 512, 0, stream>>>(B0, B4, nullptr, B1, qscale);
    // 3. chunk 1: K = rope(x*Wk) -> B2 [b,h,s,d]
    transpose_f32_bf16<<<dim3(64, 64), 256, 0, stream>>>(Wqkv + 4096, B4, 12288, 4096);
    gemm256<1><<<256, 512, 0, stream>>>(B0, B4, nullptr, B2, 1.0f);
    // 4. chunk 2: V^T = (x*Wv)^T -> B3 [b,h,d,s]
    transpose_f32_bf16<<<dim3(64, 64), 256, 0, stream>>>(Wqkv + 8192, B4, 12288, 4096);
    gemm256<2><<<256, 512, 0, stream>>>(B0, B4, nullptr, B3, 1.0f);
    // 5. Wo^T -> B4
    transpose_f32_bf16<<<dim3(64, 64), 256, 0, stream>>>(Wo, B4, 4096, 4096);
    // 6. flash attention -> ctx (B0; xb dead after chunk GEMMs)
    attn_kernel<<<dim3(32, 64), 256, 0, stream>>>(B1, B2, B3, B0);
    // 7. output projection: ctx * Wo -> fp32 out
    gemm256<0><<<256, 512, 0, stream>>>(B0, B4, out, nullptr, 1.0f);
}